// Round 4
// baseline (332.340 us; speedup 1.0000x reference)
//
#include <hip/hip_runtime.h>

// int4-dequant GEMM: y[m,n] = sum_k x[m,k] * scale[n, k/128] * (q[n,k] - 8)
// x: (512,4096) f32 | weight_packed: (11008,2048) int32 (2 nibbles in low byte) |
// scales: (11008,32) f32 | out: (512,11008) f32
//
// R11: recombination of measured-best pieces. Evidence: R7(101us,18%) > R8(120,15.7%)
// > R10(150,12%) > R9(155,11.9%) tracks (a) MFMA work per wave-iter and (b) prefetch
// depth (R8's 2-barrier reg-prefetch keeps loads in flight a FULL iter; R9/R10's
// "1-barrier" consumed loads right after MFMA -> exposed latency).
// Design: BM=BN=128, BK=64, 4 waves, wave-tile 64x64 (acc[2][2]=64 regs, 2x MFMA/
// wave-iter of R8 at half bytes/MFMA), KSPLIT=2 -> grid 688 (89.6% balance,
// 2.7 w/SIMD). Schedule = R8's 2-barrier full-iter prefetch for BOTH operands:
// B-ints -> pb regs (R7-verbatim staging/dequant -> LDS single-buf 18.4KB);
// A -> explicit paA/paB register double-buffer (static idx, rule #20) loaded
// straight from R10's verified fragment-layout xw (A never in LDS, never cold).
// VGPR ~150 -> launch_bounds(256,3) = 3 blocks/CU (12 waves vs R10's 9).
// Split-K reduce: 45MB partials, lane-coalesced layout, R7's reduce machinery
// re-derived for acc[2][2].
// Verified pieces preserved verbatim: dequant sequence, PAD=8 zero-conflict sB,
// 32x32x16 C/D mapping (col=lane&31, row=(r&3)+8*(r>>2)+4*(lane>>5)),
// fragment-layout cvt_x.

typedef __attribute__((ext_vector_type(8)))  short short8;   // 32x32x16 A/B frag
typedef __attribute__((ext_vector_type(16))) float f32x16;   // 32x32x16 C/D frag
typedef __attribute__((ext_vector_type(4)))  float f32x4;
typedef __attribute__((ext_vector_type(4)))  int   i32x4;
typedef __attribute__((ext_vector_type(2)))  int   i32x2;

#define M_DIM 512
#define N_DIM 11008
#define K_DIM 4096
#define BM 128
#define BN 128
#define BK 64
#define KSPLIT 2
#define PAD 8            // B row stride 144B: measured 0 conflicts (R5..R10)
#define THREADS 256
#define NTILE_M (M_DIM / BM)        // 4
#define NTILE_N (N_DIM / BN)        // 86
#define NTILES  (NTILE_M * NTILE_N) // 344
#define TILE_ELEMS (BM * BN)        // 16384
#define KB16    (K_DIM / 16)        // 256 k-subtiles per m-stripe

#if defined(__has_builtin)
#  if __has_builtin(__builtin_amdgcn_cvt_pk_bf16_f32)
#    define HAVE_PK_BF16 1
#  endif
#endif
#ifndef HAVE_PK_BF16
#  define HAVE_PK_BF16 0
#endif

__device__ __forceinline__ unsigned int fbits(float f) {
    union { float f; unsigned int u; } c; c.f = f; return c.u;
}
__device__ __forceinline__ int pack2bf(float lo, float hi) {  // [hi|lo] bf16, RNE
#if HAVE_PK_BF16
    typedef __attribute__((ext_vector_type(2))) __bf16 bf16x2;
    bf16x2 p = __builtin_amdgcn_cvt_pk_bf16_f32(lo, hi);
    int r; __builtin_memcpy(&r, &p, 4);
    return r;
#else
    unsigned int ul = fbits(lo), uh = fbits(hi);
    unsigned int l = (ul + 0x7FFFu + ((ul >> 16) & 1u)) >> 16;
    unsigned int h = (uh + 0x7FFFu + ((uh >> 16) & 1u)) & 0xFFFF0000u;
    return (int)(h | l);
#endif
}

// ---- x f32 -> bf16 fragment-layout workspace (verified R10) ----
// chunk c in [0, M*K/8): lane=c&63, kb16=(c>>6)&255, mb=c>>14
// m = mb*32 + (lane&31), k = kb16*16 + (lane>>5)*8
__global__ __launch_bounds__(THREADS)
void cvt_x(const float* __restrict__ x, unsigned short* __restrict__ xw)
{
    int c    = blockIdx.x * THREADS + threadIdx.x;
    int lane = c & 63;
    int kb   = (c >> 6) & (KB16 - 1);
    int mb   = c >> 14;
    int m    = mb * 32 + (lane & 31);
    int k    = kb * 16 + (lane >> 5) * 8;

    const float* src = x + (size_t)m * K_DIM + k;
    f32x4 v0 = *(const f32x4*)(src);
    f32x4 v1 = *(const f32x4*)(src + 4);
    i32x4 p;
    p[0] = pack2bf(v0[0], v0[1]);
    p[1] = pack2bf(v0[2], v0[3]);
    p[2] = pack2bf(v1[0], v1[1]);
    p[3] = pack2bf(v1[2], v1[3]);
    *(i32x4*)(xw + (size_t)c * 8) = p;
}

// ---- main GEMM: 128x128 tile, 4 waves of 64x64, 32x32x16 MFMA ----
template<int KS, bool PRECVT>
__global__ __launch_bounds__(THREADS, 3)
void dq_gemm(const unsigned short* __restrict__ xw,
             const float* __restrict__ xf,
             const int* __restrict__ wp,
             const float* __restrict__ scales,
             float* __restrict__ out,
             float* __restrict__ partials)
{
    __shared__ __align__(16) unsigned short sB[BN][BK + PAD];  // 18.4 KB, single buf

    const int t  = threadIdx.x;
    const int bx = blockIdx.x;

    int m_idx, nb, ksp;
    if (KS == 2) {
        // bx%8 = XCD (dispatch round-robin). w = per-XCD sequence + 86*xcd:
        // consecutive blocks on one XCD walk (ksp, m_idx) within the same nb
        // -> the 1 MB raw weight n-panel is reused 8x within one XCD's L2.
        int w = (bx >> 3) + 86 * (bx & 7);
        nb    = w >> 3;
        int inner = w & 7;
        ksp   = inner & 1;
        m_idx = inner >> 1;
    } else {
        m_idx = bx & 3;
        nb    = bx >> 2;
        ksp   = 0;
    }
    const int m0 = m_idx * BM;
    const int n0 = nb * BN;
    const int k0 = ksp * (K_DIM / KS);
    const int KITERS = (K_DIM / KS) / BK;    // 32 (KS=2) / 64 (KS=1)

    const int wave = t >> 6;
    const int lane = t & 63;
    const int wm = (wave & 1) * 64;    // 2 m-waves
    const int wn = (wave >> 1) * 64;   // 2 n-waves
    const int lr = lane & 31;          // frag row
    const int lk = (lane >> 5) * 8;    // frag k

    // B staging decomposition (chunk c = i*256 + t): row = i*32 + (t>>3)
    const int tr3 = t >> 3;
    const int tc4 = (t & 7) * 4;       // int col, 16B chunk

    i32x4 pb[4];
    float sc[4];

    auto LOADB = [&](int kk) {
        const int kb = k0 + kk * BK;
        const int gq = kb >> 7;
        #pragma unroll
        for (int i = 0; i < 4; ++i) {
            pb[i] = *(const i32x4*)(wp + (size_t)(n0 + i * 32 + tr3) * (K_DIM / 2) + (kb >> 1) + tc4);
            sc[i] = scales[(size_t)(n0 + i * 32 + tr3) * (K_DIM / 128) + gq];
        }
    };

    auto WRITEB = [&]() {
        #pragma unroll
        for (int i = 0; i < 4; ++i) {
            float s = sc[i], ns8 = s * -8.0f;
            i32x4 res;
            #pragma unroll
            for (int e = 0; e < 4; ++e) {
                int b = pb[i][e];
                res[e] = pack2bf((float)(b & 15) * s + ns8,
                                 (float)((b >> 4) & 15) * s + ns8);
            }
            *(i32x4*)&sB[i * 32 + tr3][tc4 * 2] = res;
        }
    };

    // A fragment source: chunk index = (mb*KB16 + kb16)*64 + lane
    const short8* xa8 = (const short8*)xw;
    const int mb0 = (m0 + wm) >> 5;

    auto LOADA = [&](int kk, short8 (&pa)[2][4]) {
        if constexpr (PRECVT) {
            const int kbb = (k0 + kk * BK) >> 4;
            #pragma unroll
            for (int s4 = 0; s4 < 4; ++s4)
                #pragma unroll
                for (int i = 0; i < 2; ++i)
                    pa[i][s4] = xa8[((size_t)(mb0 + i) * KB16 + kbb + s4) * 64 + lane];
        } else {
            #pragma unroll
            for (int s4 = 0; s4 < 4; ++s4)
                #pragma unroll
                for (int i = 0; i < 2; ++i) {
                    const float* src = xf + (size_t)(m0 + wm + i * 32 + lr) * K_DIM
                                          + k0 + kk * BK + s4 * 16 + lk;
                    f32x4 v0 = *(const f32x4*)(src);
                    f32x4 v1 = *(const f32x4*)(src + 4);
                    i32x4 p;
                    p[0] = pack2bf(v0[0], v0[1]);
                    p[1] = pack2bf(v0[2], v0[3]);
                    p[2] = pack2bf(v1[0], v1[1]);
                    p[3] = pack2bf(v1[2], v1[3]);
                    __builtin_memcpy(&pa[i][s4], &p, 16);
                }
        }
    };

    f32x16 acc[2][2] = {};

    auto MFMA_PHASE = [&](short8 (&pa)[2][4]) {
        #pragma unroll
        for (int s4 = 0; s4 < 4; ++s4) {
            short8 b[2];
            #pragma unroll
            for (int j = 0; j < 2; ++j)
                b[j] = *(const short8*)&sB[wn + j * 32 + lr][s4 * 16 + lk];
            #pragma unroll
            for (int i = 0; i < 2; ++i)
                #pragma unroll
                for (int j = 0; j < 2; ++j)
                    acc[i][j] = __builtin_amdgcn_mfma_f32_32x32x16_bf16(
                        pa[i][s4], b[j], acc[i][j], 0, 0, 0);
        }
    };

    // R8-proven 2-barrier schedule, full-iter prefetch depth, A reg-dbuf
    // (paA/paB alternation via kk-unroll-by-2 -> all static indexing).
    short8 paA[2][4], paB[2][4];

    LOADB(0);
    LOADA(0, paA);
    for (int kk = 0; kk < KITERS; kk += 2) {
        WRITEB();                         // pb(kk) -> sB
        __syncthreads();                  // sB ready
        LOADB(kk + 1);                    // in flight through MFMA + barrier
        LOADA(kk + 1, paB);
        MFMA_PHASE(paA);                  // A resident, B from LDS
        __syncthreads();                  // all waves done reading sB

        WRITEB();                         // pb(kk+1) -> sB
        __syncthreads();
        if (kk + 2 < KITERS) {
            LOADB(kk + 2);
            LOADA(kk + 2, paA);
        }
        MFMA_PHASE(paB);
        __syncthreads();
    }

    if constexpr (KS == 1) {
        // direct store: C/D col=lane&31, row=(r&3)+8*(r>>2)+4*(lane>>5)
        const int rbase = (lane >> 5) * 4;
        #pragma unroll
        for (int i = 0; i < 2; ++i) {
            int mg0 = m0 + wm + i * 32 + rbase;
            #pragma unroll
            for (int j = 0; j < 2; ++j) {
                int ng = n0 + wn + j * 32 + lr;
                #pragma unroll
                for (int r = 0; r < 16; ++r)
                    out[(size_t)(mg0 + (r & 3) + 8 * (r >> 2)) * N_DIM + ng] = acc[i][j][r];
            }
        }
    } else {
        // lane-coalesced partial store: float idx = c*1024 + t*4 + rr,
        // c = (i*2+j)*4 + q in [0,16). Each dwordx4 store lane-contiguous.
        float* my = partials + ((size_t)(m_idx * NTILE_N + nb) * KS + ksp) * TILE_ELEMS;
        #pragma unroll
        for (int i = 0; i < 2; ++i)
            #pragma unroll
            for (int j = 0; j < 2; ++j)
                #pragma unroll
                for (int q = 0; q < 4; ++q) {
                    int c = (i * 2 + j) * 4 + q;
                    f32x4 v;
                    v[0] = acc[i][j][q * 4 + 0];
                    v[1] = acc[i][j][q * 4 + 1];
                    v[2] = acc[i][j][q * 4 + 2];
                    v[3] = acc[i][j][q * 4 + 3];
                    *(f32x4*)(my + c * 1024 + t * 4) = v;
                }
    }
}

// ---- reduce: sum KSPLIT partials, frag-slot -> row-major via LDS ----
// 344 blocks, one per 128x128 tile.
__global__ __launch_bounds__(THREADS)
void reduce_k(const float* __restrict__ partials, float* __restrict__ out)
{
    __shared__ float sT[128][132];   // stride 132: 16B-aligned rows, banks ok

    const int b     = blockIdx.x;
    const int m_idx = b / NTILE_N;
    const int nb    = b % NTILE_N;
    const int m0 = m_idx * BM;
    const int n0 = nb * BN;
    const int u  = threadIdx.x;

    const float* base = partials + (size_t)b * KSPLIT * TILE_ELEMS;

    // phase 1: sum KSPLIT partials (16384 floats), scatter frag-slots into sT
    #pragma unroll
    for (int it = 0; it < 16; ++it) {
        int idx = it * 256 + u;                   // [0, 4096) f32x4-chunks
        int c   = idx >> 8;                       // [0,16)
        int t   = idx & 255;                      // gemm thread
        int off = c * 1024 + t * 4;
        f32x4 s = *(const f32x4*)(base + off);
        #pragma unroll
        for (int p = 1; p < KSPLIT; ++p)
            s += *(const f32x4*)(base + (size_t)p * TILE_ELEMS + off);
        int q = c & 3, ij = c >> 2;
        int i = ij >> 1, j = ij & 1;
        int lane = t & 63, wave = t >> 6;
        int mrow = (wave & 1) * 64 + i * 32 + 8 * q + 4 * (lane >> 5);
        int ncol = (wave >> 1) * 64 + j * 32 + (lane & 31);
        sT[mrow + 0][ncol] = s[0];
        sT[mrow + 1][ncol] = s[1];
        sT[mrow + 2][ncol] = s[2];
        sT[mrow + 3][ncol] = s[3];
    }
    __syncthreads();

    // phase 2: coalesced row-major writeout, 16B per lane
    #pragma unroll
    for (int it = 0; it < 16; ++it) {
        int idx = it * 256 + u;                   // [0, 4096)
        int row = idx >> 5;                       // 32 f32x4 per 128-col row
        int c4  = (idx & 31) * 4;
        f32x4 v = *(const f32x4*)&sT[row][c4];
        *(f32x4*)(out + (size_t)(m0 + row) * N_DIM + n0 + c4) = v;
    }
}

extern "C" void kernel_launch(void* const* d_in, const int* in_sizes, int n_in,
                              void* d_out, int out_size, void* d_ws, size_t ws_size,
                              hipStream_t stream) {
    (void)in_sizes; (void)n_in; (void)out_size;
    const float* x      = (const float*)d_in[0];
    const int*   wpck   = (const int*)d_in[1];
    const float* scales = (const float*)d_in[2];
    float*       out    = (float*)d_out;

    const size_t XW_BYTES   = (size_t)M_DIM * K_DIM * 2;                       // 4 MB
    const size_t PART_OFF   = XW_BYTES;
    const size_t PART_BYTES = (size_t)NTILES * KSPLIT * TILE_ELEMS * 4;        // 45.1 MB

    if (ws_size >= PART_OFF + PART_BYTES) {
        unsigned short* xw = (unsigned short*)d_ws;
        float* part = (float*)((char*)d_ws + PART_OFF);
        cvt_x<<<(M_DIM * K_DIM) / (THREADS * 8), THREADS, 0, stream>>>(x, xw);
        dq_gemm<KSPLIT, true><<<NTILES * KSPLIT, THREADS, 0, stream>>>(
            xw, x, wpck, scales, out, part);
        reduce_k<<<NTILES, THREADS, 0, stream>>>(part, out);
    } else if (ws_size >= XW_BYTES) {
        unsigned short* xw = (unsigned short*)d_ws;
        cvt_x<<<(M_DIM * K_DIM) / (THREADS * 8), THREADS, 0, stream>>>(x, xw);
        dq_gemm<1, true><<<NTILES, THREADS, 0, stream>>>(
            xw, x, wpck, scales, out, nullptr);
    } else {
        dq_gemm<1, false><<<NTILES, THREADS, 0, stream>>>(
            nullptr, x, wpck, scales, out, nullptr);
    }
}

// Round 5
// 224.161 us; speedup vs baseline: 1.4826x; 1.4826x over previous
//
#include <hip/hip_runtime.h>

// int4-dequant GEMM: y[m,n] = sum_k x[m,k] * scale[n, k/128] * (q[n,k] - 8)
// x: (512,4096) f32 | weight_packed: (11008,2048) int32 (2 nibbles in low byte) |
// scales: (11008,32) f32 | out: (512,11008) f32
//
// R12 = R7's proven geometry (BM=256 BN=128 BK=64, 4 waves of 128x64, acc[4][2],
// KSPLIT=4, grid 688, 2-barrier schedule, verbatim partial store + reduce_k)
// with the serial staging surgically removed:
//  1) A never touches LDS: per-fragment global loads from the verified
//     fragment-layout xw (L2-resident, 1KB/instr coalesced), areg[2][4]
//     one-step-ahead register pipeline (all static indices).
//  2) B staged RAW (same bytes; input packs 2 nibbles per int32) with zero
//     staging VALU; dequant moved into the MFMA phase (R7's exact pack2bf
//     math) where VALU overlaps the MFMA pipe.
//  3) Scales prefetched one iter ahead (full-iter depth for all load classes).
// LDS: one 18.4KB raw-B buffer; write/read = R7's measured-0-conflict
// 16B-chunks-at-144B-stride pattern. VGPR ~80 + 128 acc under (256,2): no
// spill (R11 lesson: WRITE_SIZE blowup = scratch; watch it).

typedef __attribute__((ext_vector_type(8)))  short short8;   // 32x32x16 A/B frag
typedef __attribute__((ext_vector_type(16))) float f32x16;   // 32x32x16 C/D frag
typedef __attribute__((ext_vector_type(4)))  float f32x4;
typedef __attribute__((ext_vector_type(4)))  int   i32x4;
typedef __attribute__((ext_vector_type(2)))  int   i32x2;

#define M_DIM 512
#define N_DIM 11008
#define K_DIM 4096
#define BM 256
#define BN 128
#define BK 64
#define KSPLIT 4
#define THREADS 256
#define NTILE_M (M_DIM / BM)        // 2
#define NTILE_N (N_DIM / BN)        // 86
#define NTILES  (NTILE_M * NTILE_N) // 172
#define TILE_ELEMS (BM * BN)        // 32768
#define KB16    (K_DIM / 16)        // 256 k-subtiles per 32-row m-stripe

#if defined(__has_builtin)
#  if __has_builtin(__builtin_amdgcn_cvt_pk_bf16_f32)
#    define HAVE_PK_BF16 1
#  endif
#endif
#ifndef HAVE_PK_BF16
#  define HAVE_PK_BF16 0
#endif

__device__ __forceinline__ unsigned int fbits(float f) {
    union { float f; unsigned int u; } c; c.f = f; return c.u;
}
__device__ __forceinline__ int pack2bf(float lo, float hi) {  // [hi|lo] bf16, RNE
#if HAVE_PK_BF16
    typedef __attribute__((ext_vector_type(2))) __bf16 bf16x2;
    bf16x2 p = __builtin_amdgcn_cvt_pk_bf16_f32(lo, hi);
    int r; __builtin_memcpy(&r, &p, 4);
    return r;
#else
    unsigned int ul = fbits(lo), uh = fbits(hi);
    unsigned int l = (ul + 0x7FFFu + ((ul >> 16) & 1u)) >> 16;
    unsigned int h = (uh + 0x7FFFu + ((uh >> 16) & 1u)) & 0xFFFF0000u;
    return (int)(h | l);
#endif
}

// ---- x f32 -> bf16 fragment-layout workspace (verified R10/R11) ----
// chunk c in [0, M*K/8): lane=c&63, kb16=(c>>6)&255, mb=c>>14
// m = mb*32 + (lane&31), k = kb16*16 + (lane>>5)*8
__global__ __launch_bounds__(THREADS)
void cvt_x(const float* __restrict__ x, unsigned short* __restrict__ xw)
{
    int c    = blockIdx.x * THREADS + threadIdx.x;
    int lane = c & 63;
    int kb   = (c >> 6) & (KB16 - 1);
    int mb   = c >> 14;
    int m    = mb * 32 + (lane & 31);
    int k    = kb * 16 + (lane >> 5) * 8;

    const float* src = x + (size_t)m * K_DIM + k;
    f32x4 v0 = *(const f32x4*)(src);
    f32x4 v1 = *(const f32x4*)(src + 4);
    i32x4 p;
    p[0] = pack2bf(v0[0], v0[1]);
    p[1] = pack2bf(v0[2], v0[3]);
    p[2] = pack2bf(v1[0], v1[1]);
    p[3] = pack2bf(v1[2], v1[3]);
    *(i32x4*)(xw + (size_t)c * 8) = p;
}

// ---- main GEMM: 256x128 tile, 4 waves of 128x64, 32x32x16 MFMA ----
template<int KS, bool PRECVT>
__global__ __launch_bounds__(THREADS, 2)
void dq_gemm(const unsigned short* __restrict__ xw,
             const float* __restrict__ xf,
             const int* __restrict__ wp,
             const float* __restrict__ scales,
             float* __restrict__ out,
             float* __restrict__ partials)
{
    // raw B tile: 128 rows x 32 ints, +4 int pad -> 144B stride (R7's measured
    // 0-conflict 16B@144B pattern), 18.4 KB single buffer.
    __shared__ __align__(16) int sBr[BN][32 + 4];

    const int t  = threadIdx.x;
    const int bx = blockIdx.x;

    int m_idx, nb, ksp;
    if (KS == 4) {
        // verbatim R7: bx and bx+8 land on the same XCD; pair the two m-blocks
        // of one (n,ksp) for weight L2 reuse.
        m_idx = (bx >> 3) & 1;
        int rest = (bx & 7) | ((bx >> 4) << 3);   // [0, 344)
        ksp = rest & 3;
        nb  = rest >> 2;
    } else {
        m_idx = bx & 1;
        nb  = bx >> 1;
        ksp = 0;
    }
    const int m0 = m_idx * BM;
    const int n0 = nb * BN;
    const int k0 = ksp * (K_DIM / KS);
    const int KITERS = (K_DIM / KS) / BK;   // 16 (KS=4) / 64 (KS=1)

    const int wave = t >> 6;
    const int lane = t & 63;
    const int wm = (wave & 1) * 128;   // 2 m-waves
    const int wn = (wave >> 1) * 64;   // 2 n-waves
    const int lr = lane & 31;          // frag row
    const int hi = lane >> 5;          // k-half selector
    const int lk = hi * 8;             // frag k offset

    // B staging decomposition (chunk c = i*256 + t): row = c>>3, u = c&7
    const int tr3 = t >> 3;            // row base within 32-row stripe
    const int tu  = t & 7;             // 16B chunk (4 ints) within 128B row

    i32x4 pbr[4];                      // raw B prefetch (full-iter depth)

    auto LOADB = [&](int kk) {
        const int w0 = (k0 + kk * BK) >> 1;          // int offset in row
        #pragma unroll
        for (int i = 0; i < 4; ++i)
            pbr[i] = *(const i32x4*)(wp + (size_t)(n0 + i * 32 + tr3) * (K_DIM / 2)
                                        + w0 + tu * 4);
    };

    auto WRITEB = [&]() {
        #pragma unroll
        for (int i = 0; i < 4; ++i)
            *(i32x4*)&sBr[i * 32 + tr3][tu * 4] = pbr[i];
    };

    // A fragments: direct from fragment-layout xw (no LDS).
    const short8* xa8 = (const short8*)xw;
    const int mb0 = (m0 + wm) >> 5;

    auto LOADA_STEP = [&](int kk, int s4, short8 (&dst)[4]) {
        if constexpr (PRECVT) {
            const int kb16 = ((k0 + kk * BK) >> 4) + s4;
            #pragma unroll
            for (int i = 0; i < 4; ++i)
                dst[i] = xa8[((size_t)(mb0 + i) * KB16 + kb16) * 64 + lane];
        } else {
            #pragma unroll
            for (int i = 0; i < 4; ++i) {
                const float* src = xf + (size_t)(m0 + wm + i * 32 + lr) * K_DIM
                                      + k0 + kk * BK + s4 * 16 + lk;
                f32x4 v0 = *(const f32x4*)(src);
                f32x4 v1 = *(const f32x4*)(src + 4);
                i32x4 p;
                p[0] = pack2bf(v0[0], v0[1]);
                p[1] = pack2bf(v0[2], v0[3]);
                p[2] = pack2bf(v1[0], v1[1]);
                p[3] = pack2bf(v1[2], v1[3]);
                __builtin_memcpy(&dst[i], &p, 16);
            }
        }
    };

    f32x16 acc[4][2] = {};

    // consumer-side B dequant: R7's exact math, from raw ints in LDS.
    auto BFRAG = [&](int s4, int j, float s, float ns8) -> short8 {
        i32x4 braw = *(const i32x4*)&sBr[wn + j * 32 + lr][s4 * 8 + hi * 4];
        i32x4 rr;
        #pragma unroll
        for (int e = 0; e < 4; ++e) {
            int b = braw[e];
            rr[e] = pack2bf((float)(b & 15) * s + ns8,
                            (float)((b >> 4) & 15) * s + ns8);
        }
        short8 bf; __builtin_memcpy(&bf, &rr, 16);
        return bf;
    };

    // scale row indices for this wave's two n-frags
    const size_t srow0 = (size_t)(n0 + wn + lr)      * (K_DIM / 128);
    const size_t srow1 = (size_t)(n0 + wn + 32 + lr) * (K_DIM / 128);

    short8 areg[2][4];

    // prologue: full-iter prefetch of everything for kk=0
    LOADB(0);
    LOADA_STEP(0, 0, areg[0]);
    float sc0 = scales[srow0 + (k0 >> 7)];
    float sc1 = scales[srow1 + (k0 >> 7)];

    for (int kk = 0; kk < KITERS; ++kk) {
        WRITEB();                    // 4 ds_write_b128 (waits pbr vmcnt)
        __syncthreads();             // sBr ready

        float nx0 = sc0, nx1 = sc1;
        if (kk + 1 < KITERS) {
            LOADB(kk + 1);           // in flight across the whole MFMA phase
            const int gq = (k0 + (kk + 1) * BK) >> 7;
            nx0 = scales[srow0 + gq];
            nx1 = scales[srow1 + gq];
        }
        const float s0 = sc0, n80 = sc0 * -8.0f;
        const float s1 = sc1, n81 = sc1 * -8.0f;

        #pragma unroll
        for (int s4 = 0; s4 < 4; ++s4) {
            const int cur = s4 & 1;
            // issue next-step A loads (land under this step's MFMAs)
            if (s4 < 3)
                LOADA_STEP(kk, s4 + 1, areg[cur ^ 1]);
            else if (kk + 1 < KITERS)
                LOADA_STEP(kk + 1, 0, areg[cur ^ 1]);

            short8 b0 = BFRAG(s4, 0, s0, n80);
            short8 b1 = BFRAG(s4, 1, s1, n81);
            #pragma unroll
            for (int i = 0; i < 4; ++i) {
                acc[i][0] = __builtin_amdgcn_mfma_f32_32x32x16_bf16(
                    areg[cur][i], b0, acc[i][0], 0, 0, 0);
                acc[i][1] = __builtin_amdgcn_mfma_f32_32x32x16_bf16(
                    areg[cur][i], b1, acc[i][1], 0, 0, 0);
            }
        }
        __syncthreads();             // all waves done reading sBr
        sc0 = nx0; sc1 = nx1;
    }

    const int rbase = hi * 4;
    if constexpr (KS == 1) {
        // direct store: C/D col=lane&31, row=(r&3)+8*(r>>2)+4*(lane>>5)
        #pragma unroll
        for (int i = 0; i < 4; ++i) {
            int mg0 = m0 + wm + i * 32 + rbase;
            #pragma unroll
            for (int j = 0; j < 2; ++j) {
                int ng = n0 + wn + j * 32 + lr;
                #pragma unroll
                for (int r = 0; r < 16; ++r)
                    out[(size_t)(mg0 + (r & 3) + 8 * (r >> 2)) * N_DIM + ng] = acc[i][j][r];
            }
        }
    } else {
        // verbatim R7 lane-coalesced partial store: float index = c*1024 + t*4,
        // c = (i*2+j)*4 + q in [0,32). Each dwordx4 store is lane-contiguous.
        float* my = partials + ((size_t)(m_idx * NTILE_N + nb) * KS + ksp) * TILE_ELEMS;
        #pragma unroll
        for (int i = 0; i < 4; ++i)
            #pragma unroll
            for (int j = 0; j < 2; ++j)
                #pragma unroll
                for (int q = 0; q < 4; ++q) {
                    int c = (i * 2 + j) * 4 + q;
                    f32x4 v;
                    v[0] = acc[i][j][q * 4 + 0];
                    v[1] = acc[i][j][q * 4 + 1];
                    v[2] = acc[i][j][q * 4 + 2];
                    v[3] = acc[i][j][q * 4 + 3];
                    *(f32x4*)(my + c * 1024 + t * 4) = v;
                }
    }
}

// ---- reduce: verbatim R7. sum 4 partials, frag-slot -> row-major via LDS ----
// 344 blocks: block b handles m-half h of tile b>>1 (128 rows x 128 cols).
__global__ __launch_bounds__(THREADS)
void reduce_k(const float* __restrict__ partials, float* __restrict__ out)
{
    __shared__ float sT[128][132];   // stride 132: 16B-aligned rows, banks ok

    const int b    = blockIdx.x;
    const int tile = b >> 1;
    const int h    = b & 1;                       // m-half within the 256-row tile
    const int m_idx = tile / NTILE_N;
    const int nb    = tile % NTILE_N;
    const int m0 = m_idx * BM + h * 128;
    const int n0 = nb * BN;
    const int u  = threadIdx.x;

    const float* base = partials + (size_t)tile * KSPLIT * TILE_ELEMS;

    // phase 1: sum partials for this half's 16384 floats, scatter into sT
    #pragma unroll
    for (int it = 0; it < 16; ++it) {
        int idx = it * 256 + u;                   // [0, 4096) f32x4-chunks
        int c   = idx >> 7;                       // [0,32)
        int tl  = idx & 127;
        int t   = (tl & 63) | (h << 6) | ((tl & 64) << 1);  // threads with wave&1==h
        int off = c * 1024 + t * 4;
        f32x4 s = *(const f32x4*)(base + off);
        s += *(const f32x4*)(base + TILE_ELEMS + off);
        s += *(const f32x4*)(base + 2 * TILE_ELEMS + off);
        s += *(const f32x4*)(base + 3 * TILE_ELEMS + off);
        int i = c >> 3, j = (c >> 2) & 1, q = c & 3;
        int lane = t & 63, wave = t >> 6;
        int mrow = i * 32 + (lane >> 5) * 4 + 8 * q;        // [0,128) within half
        int ncol = (wave >> 1) * 64 + j * 32 + (lane & 31);
        sT[mrow + 0][ncol] = s[0];
        sT[mrow + 1][ncol] = s[1];
        sT[mrow + 2][ncol] = s[2];
        sT[mrow + 3][ncol] = s[3];
    }
    __syncthreads();

    // phase 2: coalesced row-major writeout, 16B per lane
    #pragma unroll
    for (int it = 0; it < 16; ++it) {
        int idx = it * 256 + u;                   // [0, 4096)
        int row = idx >> 5;                       // 32 f32x4 per 128-col row
        int c4  = (idx & 31) * 4;
        f32x4 v = *(const f32x4*)&sT[row][c4];
        *(f32x4*)(out + (size_t)(m0 + row) * N_DIM + n0 + c4) = v;
    }
}

extern "C" void kernel_launch(void* const* d_in, const int* in_sizes, int n_in,
                              void* d_out, int out_size, void* d_ws, size_t ws_size,
                              hipStream_t stream) {
    (void)in_sizes; (void)n_in; (void)out_size;
    const float* x      = (const float*)d_in[0];
    const int*   wpck   = (const int*)d_in[1];
    const float* scales = (const float*)d_in[2];
    float*       out    = (float*)d_out;

    const size_t XW_BYTES   = (size_t)M_DIM * K_DIM * 2;                        // 4 MB
    const size_t PART_OFF   = XW_BYTES;
    const size_t PART_BYTES = (size_t)NTILES * KSPLIT * TILE_ELEMS * 4;         // 90.2 MB

    if (ws_size >= PART_OFF + PART_BYTES) {
        unsigned short* xw  = (unsigned short*)d_ws;
        float* part = (float*)((char*)d_ws + PART_OFF);
        cvt_x<<<(M_DIM * K_DIM) / (THREADS * 8), THREADS, 0, stream>>>(x, xw);
        dq_gemm<KSPLIT, true><<<NTILES * KSPLIT, THREADS, 0, stream>>>(
            xw, x, wpck, scales, out, part);
        reduce_k<<<NTILES * 2, THREADS, 0, stream>>>(part, out);
    } else if (ws_size >= XW_BYTES) {
        unsigned short* xw = (unsigned short*)d_ws;
        cvt_x<<<(M_DIM * K_DIM) / (THREADS * 8), THREADS, 0, stream>>>(x, xw);
        dq_gemm<1, true><<<NTILES, THREADS, 0, stream>>>(
            xw, x, wpck, scales, out, nullptr);
    } else {
        dq_gemm<1, false><<<NTILES, THREADS, 0, stream>>>(
            nullptr, x, wpck, scales, out, nullptr);
    }
}